// Round 1
// baseline (1159.784 us; speedup 1.0000x reference)
//
#include <hip/hip_runtime.h>

// Fourier layer: out[b,x,y,o] = irfft_y(wx·rfft_y(x))[o] + irfft_x(wy·rfft_x(x))[o]
// B=16, X=Y=256, C=64, MODES=32, norm="ortho" (1/16 each way).
// Pipeline per direction: fwd (DFT->32 modes) -> mix (channel GEMM, in-place) -> inv.
// Workspace: C coeff buffer 64MB + TWf 64KB + TWiT 64KB + WT1/WT2 1MB each.

#define SP 256
#define CH 64
#define MODES 32
#define KK 64                 // 2*MODES (Re/Im interleaved rows)
#define SLICE (KK*CH)         // 4096 floats per (b,r) coefficient tile
#define XSTRIDE_B 4194304     // 256*256*64
#define XSTRIDE_N 16384       // 256*64

// ---------------- table builders (run every launch; ws is re-poisoned) --------
__global__ __launch_bounds__(256) void build_tw(float* __restrict__ TWf,
                                                float* __restrict__ TWiT) {
    int t = blockIdx.x * 256 + threadIdx.x;        // 8192 = 256 m * 32 k
    if (t >= SP * MODES) return;
    int m = t >> 5, k = t & 31;
    int idx = (k * m) & 255;                       // periodic reduction: exact angle
    float ang = (float)idx * 0.02454369260617026f; // 2*pi/256
    float c = cosf(ang), s = sinf(ang);
    // forward: X_re[k] = (1/16) sum v*cos ; X_im[k] = -(1/16) sum v*sin
    TWf[m * KK + 2 * k]     =  c * 0.0625f;
    TWf[m * KK + 2 * k + 1] = -s * 0.0625f;
    // inverse (C2R): out[m] = (1/16)ReZ0 + (1/8) sum_{k>=1} (ReZk cos - ImZk sin)
    // k=0 Im coefficient = -a*sin(0) = 0  -> DC imag ignored, matching irfft.
    float a = (k == 0) ? 0.0625f : 0.125f;
    TWiT[(2 * k) * SP + m]     =  a * c;
    TWiT[(2 * k + 1) * SP + m] = -a * s;
}

// transpose weights [i][o][k][ri] -> WT[kk=2k+ri][i][o]  (coalesced mix reads)
__global__ __launch_bounds__(256) void build_wt(const float* __restrict__ w1,
                                                const float* __restrict__ w2,
                                                float* __restrict__ WT1,
                                                float* __restrict__ WT2) {
    int t = blockIdx.x * 256 + threadIdx.x;        // 2 * 262144
    int e = t & 262143;
    int o = e & 63, i = (e >> 6) & 63, kk = e >> 12;
    int k = kk >> 1, ri = kk & 1;
    const float* src = (t < 262144) ? w1 : w2;
    float*       dst = (t < 262144) ? WT1 : WT2;
    dst[e] = src[((i * 64 + o) * MODES + k) * 2 + ri];
}

// ---------------- stage 1: forward DFT to 32 modes ----------------------------
// grid 4096 = (b, r); thread (i = t&63, kq = t>>6) accumulates 16 kk rows for
// its channel column. Twiddles via wave-uniform s_load; x via coalesced 256B rows.
__global__ __launch_bounds__(256) void fwd_kernel(const float* __restrict__ x,
                                                  float* __restrict__ C,
                                                  const float* __restrict__ TWf,
                                                  int row_stride, int slice_stride) {
    int bid = blockIdx.x;
    int b = bid >> 8, r = bid & 255;
    int t = threadIdx.x;
    int i = t & 63;
    int kq = __builtin_amdgcn_readfirstlane(t >> 6);   // wave-uniform -> SGPR
    const float* src = x + (size_t)b * XSTRIDE_B + (size_t)r * slice_stride + i;
    const float4* tw = (const float4*)TWf + kq * 4;    // row m at tw[m*16 .. +3]
    float4 a0 = {0,0,0,0}, a1 = a0, a2 = a0, a3 = a0;
    #pragma unroll 4
    for (int m = 0; m < 256; ++m) {
        float v = src[(size_t)m * row_stride];
        float4 t0 = tw[m*16+0], t1 = tw[m*16+1], t2 = tw[m*16+2], t3 = tw[m*16+3];
        a0.x += t0.x*v; a0.y += t0.y*v; a0.z += t0.z*v; a0.w += t0.w*v;
        a1.x += t1.x*v; a1.y += t1.y*v; a1.z += t1.z*v; a1.w += t1.w*v;
        a2.x += t2.x*v; a2.y += t2.y*v; a2.z += t2.z*v; a2.w += t2.w*v;
        a3.x += t3.x*v; a3.y += t3.y*v; a3.z += t3.z*v; a3.w += t3.w*v;
    }
    float* dst = C + (size_t)bid * SLICE + kq * 16 * 64 + i;  // [b][r][kk][i]
    dst[0*64]=a0.x; dst[1*64]=a0.y; dst[2*64]=a0.z; dst[3*64]=a0.w;
    dst[4*64]=a1.x; dst[5*64]=a1.y; dst[6*64]=a1.z; dst[7*64]=a1.w;
    dst[8*64]=a2.x; dst[9*64]=a2.y; dst[10*64]=a2.z; dst[11*64]=a2.w;
    dst[12*64]=a3.x; dst[13*64]=a3.y; dst[14*64]=a3.z; dst[15*64]=a3.w;
}

// ---------------- stage 2: per-mode complex channel mix (in-place) ------------
// grid 512 = (b, k). Batches all 256 slices of one (b,k) so the 32KB weight
// slice is read once per block (not once per slice). LDS-transposes X so the
// i-loop reads contiguous n-runs. In-place: block only touches its own kk rows.
__global__ __launch_bounds__(256) void mix_kernel(float* __restrict__ C,
                                                  const float* __restrict__ WT) {
    int bid = blockIdx.x;
    int b = bid >> 5, k = bid & 31;
    int t = threadIdx.x;
    int o = t & 63, nq = t >> 6;
    __shared__ float XT[2][64][68];     // [ri][i][n_local], pad 68: aligned f4 reads
    const float* wRe_base = WT + (2 * k) * 4096;       // [i][o]
    const float* wIm_base = WT + (2 * k + 1) * 4096;
    for (int nt = 0; nt < 4; ++nt) {
        __syncthreads();
        #pragma unroll
        for (int jj = 0; jj < 32; ++jj) {
            int flat = t + jj * 256;                   // 64n * 2ri * 64i
            int n_l = flat >> 7, ri = (flat >> 6) & 1, ii = flat & 63;
            XT[ri][ii][n_l] =
                C[(size_t)((b * 256 + nt * 64 + n_l) * 64 + 2 * k + ri) * 64 + ii];
        }
        __syncthreads();
        float accRe[16], accIm[16];
        #pragma unroll
        for (int j = 0; j < 16; ++j) { accRe[j] = 0.f; accIm[j] = 0.f; }
        #pragma unroll 2
        for (int ii = 0; ii < 64; ++ii) {
            float wRe = wRe_base[ii * 64 + o];         // L1-hot, coalesced
            float wIm = wIm_base[ii * 64 + o];
            const float4* xr = (const float4*)&XT[0][ii][nq * 16];
            const float4* xi = (const float4*)&XT[1][ii][nq * 16];
            #pragma unroll
            for (int q = 0; q < 4; ++q) {
                float4 vr = xr[q], vi = xi[q];
                accRe[q*4+0] += wRe*vr.x - wIm*vi.x;  accIm[q*4+0] += wRe*vi.x + wIm*vr.x;
                accRe[q*4+1] += wRe*vr.y - wIm*vi.y;  accIm[q*4+1] += wRe*vi.y + wIm*vr.y;
                accRe[q*4+2] += wRe*vr.z - wIm*vi.z;  accIm[q*4+2] += wRe*vi.z + wIm*vr.z;
                accRe[q*4+3] += wRe*vr.w - wIm*vi.w;  accIm[q*4+3] += wRe*vi.w + wIm*vr.w;
            }
        }
        #pragma unroll
        for (int j = 0; j < 16; ++j) {
            int n = nt * 64 + nq * 16 + j;
            size_t dst = (size_t)((b * 256 + n) * 64 + 2 * k) * 64 + o;
            C[dst]      = accRe[j];
            C[dst + 64] = accIm[j];
        }
    }
}

// ---------------- stage 3: inverse DFT + write/accumulate out -----------------
// grid 4096 = (b, r). Z tile staged in LDS (conflict-free reads across o lanes);
// twiddles via wave-uniform s_load (TWiT is kk-major so each thread's 16 m are
// contiguous). add=1 for the second direction (read-modify-write).
__global__ __launch_bounds__(256) void inv_kernel(const float* __restrict__ C,
                                                  const float* __restrict__ TWiT,
                                                  float* __restrict__ out,
                                                  int row_stride, int slice_stride,
                                                  int add) {
    int bid = blockIdx.x;
    int b = bid >> 8, r = bid & 255;
    int t = threadIdx.x;
    int o = t & 63;
    int mq = __builtin_amdgcn_readfirstlane(t >> 6);
    __shared__ float ZT[SLICE];
    #pragma unroll
    for (int jj = 0; jj < 16; ++jj)
        ZT[t + jj * 256] = C[(size_t)bid * SLICE + t + jj * 256];
    __syncthreads();
    float* obase = out + (size_t)b * XSTRIDE_B + (size_t)r * slice_stride + o;
    for (int mt = 0; mt < 4; ++mt) {
        int m0 = mt * 64 + mq * 16;
        float4 a0 = {0,0,0,0}, a1 = a0, a2 = a0, a3 = a0;
        #pragma unroll 2
        for (int kk = 0; kk < 64; ++kk) {
            float z = ZT[kk * 64 + o];
            const float4* tw = (const float4*)(TWiT + kk * SP + m0);
            float4 t0 = tw[0], t1 = tw[1], t2 = tw[2], t3 = tw[3];
            a0.x += t0.x*z; a0.y += t0.y*z; a0.z += t0.z*z; a0.w += t0.w*z;
            a1.x += t1.x*z; a1.y += t1.y*z; a1.z += t1.z*z; a1.w += t1.w*z;
            a2.x += t2.x*z; a2.y += t2.y*z; a2.z += t2.z*z; a2.w += t2.w*z;
            a3.x += t3.x*z; a3.y += t3.y*z; a3.z += t3.z*z; a3.w += t3.w*z;
        }
        float av[16] = {a0.x,a0.y,a0.z,a0.w, a1.x,a1.y,a1.z,a1.w,
                        a2.x,a2.y,a2.z,a2.w, a3.x,a3.y,a3.z,a3.w};
        #pragma unroll
        for (int j = 0; j < 16; ++j) {
            size_t addr = (size_t)(m0 + j) * row_stride;
            float v = av[j];
            if (add) v += obase[addr];
            obase[addr] = v;
        }
    }
}

extern "C" void kernel_launch(void* const* d_in, const int* in_sizes, int n_in,
                              void* d_out, int out_size, void* d_ws, size_t ws_size,
                              hipStream_t stream) {
    const float* x  = (const float*)d_in[0];
    const float* w1 = (const float*)d_in[1];
    const float* w2 = (const float*)d_in[2];
    float* out = (float*)d_out;

    float* C    = (float*)d_ws;          // 16,777,216 floats (64 MB), reused per dir
    float* TWf  = C + 16777216;          // 16,384
    float* TWiT = TWf + 16384;           // 16,384
    float* WT1  = TWiT + 16384;          // 262,144
    float* WT2  = WT1 + 262144;          // 262,144  -> total ~69.3 MB

    build_tw<<<32, 256, 0, stream>>>(TWf, TWiT);
    build_wt<<<2048, 256, 0, stream>>>(w1, w2, WT1, WT2);

    // conv along Y (reference rfft axis=-2, weights w1): slices (b, n=x-index)
    fwd_kernel<<<4096, 256, 0, stream>>>(x, C, TWf, /*row*/64, /*slice*/XSTRIDE_N);
    mix_kernel<<<512, 256, 0, stream>>>(C, WT1);
    inv_kernel<<<4096, 256, 0, stream>>>(C, TWiT, out, 64, XSTRIDE_N, 0);

    // conv along X (reference rfft axis=-1, weights w2): slices (b, m=y-index)
    fwd_kernel<<<4096, 256, 0, stream>>>(x, C, TWf, XSTRIDE_N, 64);
    mix_kernel<<<512, 256, 0, stream>>>(C, WT2);
    inv_kernel<<<4096, 256, 0, stream>>>(C, TWiT, out, XSTRIDE_N, 64, 1);
}